// Round 6
// baseline (368.167 us; speedup 1.0000x reference)
//
#include <hip/hip_runtime.h>

#define NN 65536
#define HH 64
#define NBLK 1024  // 4 blocks/CU x 256 CUs: co-resident by capacity
#define EPSF 1e-5f
#define C1 0.0625f
#define NREP 32  // stats accumulator replicas (contention spread)

typedef short bf16x8 __attribute__((ext_vector_type(8)));
typedef short s16x4 __attribute__((ext_vector_type(4)));
typedef float f32x4 __attribute__((ext_vector_type(4)));
typedef unsigned short u16;

#define MFMA(a, b, c) __builtin_amdgcn_mfma_f32_16x16x32_bf16(a, b, c, 0, 0, 0)

__device__ __forceinline__ u16 f2bf(float x) {
  union { float f; unsigned u; } v; v.f = x; return (u16)(v.u >> 16);
}
__device__ __forceinline__ float bf2f(u16 h) {
  union { float f; unsigned u; } v; v.u = ((unsigned)h) << 16; return v.f;
}
__device__ __forceinline__ void split2(float x, u16& h, u16& l) {
  h = f2bf(x); l = f2bf(x - bf2f(h));
}
// swizzled index into a 64x64 u16 LDS tile: 16B granules XOR'd by row&7
__device__ __forceinline__ int XIDX(int r, int c) {
  return r * 64 + ((((c >> 3) ^ (r & 7)) << 3) | (c & 7));
}

// Build local adjacency (multiplicity) for this graph into Adj (bf16, swizzled).
__device__ __forceinline__ void build_adj(const int* __restrict__ src, int g,
                                          int r, u16* Adj) {
  bf16x8 z = {0, 0, 0, 0, 0, 0, 0, 0};
#pragma unroll
  for (int q = 0; q < 8; q++) *(bf16x8*)&Adj[r * 64 + q * 8] = z;
  const int4* s4 = (const int4*)(src + (size_t)g * 1024 + (size_t)r * 16);
  int4 a0 = s4[0], a1 = s4[1], a2 = s4[2], a3 = s4[3];
  int b0 = g * 64;
  int ss[16] = {a0.x - b0, a0.y - b0, a0.z - b0, a0.w - b0,
                a1.x - b0, a1.y - b0, a1.z - b0, a1.w - b0,
                a2.x - b0, a2.y - b0, a2.z - b0, a2.w - b0,
                a3.x - b0, a3.y - b0, a3.z - b0, a3.w - b0};
#pragma unroll
  for (int e = 0; e < 16; e++) {
    int idx = XIDX(r, ss[e]);
    Adj[idx] = f2bf(bf2f(Adj[idx]) + 1.0f);
  }
}

// ===========================================================================
// FUSED KERNEL v3: 1024 blocks x 256 thr, __launch_bounds__(256,4), LDS
// exactly 40960 B (5 tiles) -> 4 blocks/CU, all 1024 co-resident (capacity).
// One graph per block. Pre-BN activations in registers. Occupancy doubled
// vs round 5 (2->4 blocks/CU) to hide the latency-bound phase structure.
// LDS plan (u16 idx): NMh[0..4095] NMl[4096..8191] CMh[8192..12287]
//   CMl[12288..16383] Adj[16384..20479].
//   X1's col-major copy reuses CMh/CMl in place (in-lap WAR sync).
//   econv aliases: Tf float[64*68]=17408B over CMh+CMl+Adj head;
//   sW u32[256] over Adj tail; sstats float[128] over Adj head (transient:
//   consumed into reg sc/sh right after each barrier -- BN scale/shift are
//   graph-invariant so they live in 8 VGPRs, not LDS).
// Cross-block: stats via device atomicAdd (32 replicas) + agent RELAXED
// atomic loads; barrier = RELAXED fetch_add + RELAXED spin (round-5 lesson:
// no acquire/release cache maintenance -- all shared data is L3 atomics).
// ===========================================================================
struct KP {
  const float* feat; const int* src;
  const u16 *W1h, *W1l, *W2h, *W2l, *W3h, *W3l;
  const u16 *T1h, *T1l, *P1h, *P1l, *T2h, *T2l, *P2h, *P2l;
  const float *c1b, *bn1g, *bn1b;
  const float *e1tb, *e1pb, *bne1g, *bne1b;
  const float *c2b, *bn2g, *bn2b;
  const float *e2tb, *e2pb, *bne2g, *bne2b;
  const float *c3b, *bn3g, *bn3b;
  float* stats;   // 5 x NREP x 128
  unsigned* bar;  // 8 barrier counters (zeroed by k_prep each iteration)
  float* out;
};

__global__ __launch_bounds__(256, 4) void k_fused(KP p) {
  __shared__ __align__(16) u16 SH[20480];  // 40960 B exactly -> 4 blocks/CU
  u16* NMh = SH;
  u16* NMl = SH + 4096;
  u16* CMh = SH + 8192;
  u16* CMl = SH + 12288;
  u16* Adj = SH + 16384;
  float* Tf = (float*)(SH + 8192);         // econv: 17408 B
  unsigned* sW = (unsigned*)(SH + 19968);  // econv: 1 KB (Adj tail)
  float* sstats = (float*)(SH + 16384);    // transient (Adj head)

  const int t = threadIdx.x;
  const int L = t & 63;
  const int w = __builtin_amdgcn_readfirstlane(t >> 6);
  const int ml = L & 15, kq = L >> 4;
  const int c0 = w * 16 + kq * 4;  // this thread's 4 output channels
  const int g = blockIdx.x;        // this block's graph

  f32x4 y[4];          // pre-BN y frags: [nt] -> node nt*16+ml, ch c0..c0+3
  float sc[4], sh[4];  // current boundary's BN scale/shift (graph-invariant)

  // RELAXED grid barrier on counter i. __syncthreads drains vmcnt first ->
  // this block's stats atomics are at L3 before arrival. Timeout ~40ms.
  auto gbar = [&](int i) {
    __syncthreads();
    if (t == 0) {
      unsigned* c = p.bar + i;
      __hip_atomic_fetch_add(c, 1u, __ATOMIC_RELAXED,
                             __HIP_MEMORY_SCOPE_AGENT);
      unsigned long long tstart = __builtin_amdgcn_s_memrealtime();
      while (__hip_atomic_load(c, __ATOMIC_RELAXED,
                               __HIP_MEMORY_SCOPE_AGENT) < (unsigned)NBLK) {
        __builtin_amdgcn_s_sleep(8);
        if (__builtin_amdgcn_s_memrealtime() - tstart > 4000000ull) break;
      }
    }
    __syncthreads();
  };

  // Post-barrier: replica-sum stats into transient sstats, fold into reg
  // sc/sh, release the LDS (trailing sync) for Adj/Tf reuse.
  auto bn_coeffs = [&](const float* sb, const float* gam, const float* bet) {
    if (t < 128) {
      float s = 0.f;
#pragma unroll
      for (int r = 0; r < NREP; r++)
        s += __hip_atomic_load(sb + (size_t)r * 128 + t, __ATOMIC_RELAXED,
                               __HIP_MEMORY_SCOPE_AGENT);
      sstats[t] = s;
    }
    __syncthreads();
    const float inv = 1.0f / (float)NN;
#pragma unroll
    for (int i = 0; i < 4; i++) {
      int c = c0 + i;
      float s1 = sstats[c], s2 = sstats[64 + c];
      float mu = s1 * inv;
      float var = fmaf(s2, inv, -mu * mu);
      sc[i] = gam[c] * rsqrtf(var + EPSF);
      sh[i] = fmaf(-mu, sc[i], bet[c]);
    }
    __syncthreads();  // sstats consumed; Adj/Tf may overwrite
  };

  auto stats_acc = [&](float* so) {
    float s1[4] = {0, 0, 0, 0}, s2[4] = {0, 0, 0, 0};
#pragma unroll
    for (int nt = 0; nt < 4; nt++)
#pragma unroll
      for (int i = 0; i < 4; i++) {
        s1[i] += y[nt][i];
        s2[i] += y[nt][i] * y[nt][i];
      }
#pragma unroll
    for (int i = 0; i < 4; i++)
#pragma unroll
      for (int off = 1; off < 16; off <<= 1) {
        s1[i] += __shfl_xor(s1[i], off, 64);
        s2[i] += __shfl_xor(s2[i], off, 64);
      }
    if (ml == 0) {
      float* pr = so + (size_t)(g & (NREP - 1)) * 128 + c0;
#pragma unroll
      for (int i = 0; i < 4; i++) {
        atomicAdd(pr + i, s1[i]);
        atomicAdd(pr + 64 + i, s2[i]);
      }
    }
  };

  // BN+ReLU from frags (reg sc/sh) -> NM tiles (+ CM col-major if writeCM).
  auto bn_frag = [&](bool writeCM) {
#pragma unroll
    for (int nt = 0; nt < 4; nt++) {
      int node = nt * 16 + ml;
      u16 hh[4], ll[4];
      s16x4 vh, vl;
#pragma unroll
      for (int i = 0; i < 4; i++) {
        float h = fmaxf(fmaf(sc[i], y[nt][i], sh[i]), 0.f);
        split2(h, hh[i], ll[i]);
        vh[i] = (short)hh[i]; vl[i] = (short)ll[i];
      }
      *(s16x4*)&NMh[XIDX(node, c0)] = vh;
      *(s16x4*)&NMl[XIDX(node, c0)] = vl;
      if (writeCM) {
#pragma unroll
        for (int i = 0; i < 4; i++) {
          CMh[XIDX(c0 + i, node)] = hh[i];
          CMl[XIDX(c0 + i, node)] = ll[i];
        }
      }
    }
  };

  // ---- cheb layer CI=64 (W folded [W0-W2|W1|W2], K=192) ----
  auto cheb64_graph = [&](const u16* wh, const u16* wl, const float* bias,
                          float* so) {
    bn_frag(true);
    if (w == 3) build_adj(p.src, g, L, Adj);
    __syncthreads();

    f32x4 acc[4] = {};
    auto yacc = [&](int kbase) {
      const u16* whp = wh + (size_t)(w * 16 + ml) * 192 + kq * 8 + kbase;
      const u16* wlp = wl + (size_t)(w * 16 + ml) * 192 + kq * 8 + kbase;
#pragma unroll
      for (int kt = 0; kt < 2; kt++) {
        bf16x8 ah = *(const bf16x8*)(whp + kt * 32);
        bf16x8 al = *(const bf16x8*)(wlp + kt * 32);
        int kk = kt * 32 + kq * 8;
#pragma unroll
        for (int nt = 0; nt < 4; nt++) {
          bf16x8 bh = *(const bf16x8*)&NMh[XIDX(nt * 16 + ml, kk)];
          bf16x8 bl = *(const bf16x8*)&NMl[XIDX(nt * 16 + ml, kk)];
          acc[nt] = MFMA(ah, bh, acc[nt]);
          acc[nt] = MFMA(al, bh, acc[nt]);
          acc[nt] = MFMA(ah, bl, acc[nt]);
        }
      }
    };
    // lap: L = Adj * X (X read col-major from CM). Writes node-major into NM
    // and, if writeCM, col-major IN PLACE over CM (freed 16 KB vs dedicated
    // X1 tiles). In-lap __syncthreads separates all CM reads from CM writes.
    auto lap = [&](float scale, bool writeCM) {
      f32x4 l[4] = {};
#pragma unroll
      for (int kt = 0; kt < 2; kt++) {
        int kk = kt * 32 + kq * 8;
        bf16x8 aa = *(const bf16x8*)&Adj[XIDX(w * 16 + ml, kk)];
#pragma unroll
        for (int nt = 0; nt < 4; nt++) {
          bf16x8 bh = *(const bf16x8*)&CMh[XIDX(nt * 16 + ml, kk)];
          bf16x8 bl = *(const bf16x8*)&CMl[XIDX(nt * 16 + ml, kk)];
          l[nt] = MFMA(aa, bh, l[nt]);
          l[nt] = MFMA(aa, bl, l[nt]);
        }
      }
      if (writeCM) __syncthreads();  // WAR: CM writes below vs CM reads above
      int r0 = w * 16 + kq * 4;
#pragma unroll
      for (int nt = 0; nt < 4; nt++) {
        int c = nt * 16 + ml;
        u16 hh[4], ll[4];
#pragma unroll
        for (int i = 0; i < 4; i++) {
          split2(l[nt][i] * scale, hh[i], ll[i]);
          NMh[XIDX(r0 + i, c)] = hh[i];
          NMl[XIDX(r0 + i, c)] = ll[i];
        }
        if (writeCM) {
          s16x4 vh, vl;
#pragma unroll
          for (int i = 0; i < 4; i++) {
            vh[i] = (short)hh[i]; vl[i] = (short)ll[i];
          }
          *(s16x4*)&CMh[XIDX(c, r0)] = vh;
          *(s16x4*)&CMl[XIDX(c, r0)] = vl;
        }
      }
    };

    yacc(0);                  // X0 vs W0' = W0 - W2
    __syncthreads();
    lap(-C1, true);           // X1 = -C1*Adj*X0 -> NM + CM (in place)
    __syncthreads();
    yacc(64);                 // X1 vs W1
    __syncthreads();
    lap(-2.0f * C1, false);   // Z2 = -2C1*Adj*X1 -> NM
    __syncthreads();
    yacc(128);                // Z2 vs W2
    float4 bb = *(const float4*)(bias + c0);
#pragma unroll
    for (int nt = 0; nt < 4; nt++) {
      y[nt][0] = acc[nt][0] + bb.x;
      y[nt][1] = acc[nt][1] + bb.y;
      y[nt][2] = acc[nt][2] + bb.z;
      y[nt][3] = acc[nt][3] + bb.w;
    }
    stats_acc(so);
  };

  // ---- econv layer ----
  auto econv_graph = [&](const u16* twh, const u16* twl, const u16* pwh,
                         const u16* pwl, const float* tb, const float* pb,
                         float* so) {
    int4 v = ((const int4*)(p.src + (size_t)g * 1024))[t];  // early issue
    bn_frag(false);
    {
      int b0 = g * 64;
      sW[t] = (unsigned)(v.x - b0) | ((unsigned)(v.y - b0) << 8) |
              ((unsigned)(v.z - b0) << 16) | ((unsigned)(v.w - b0) << 24);
    }
    __syncthreads();

    f32x4 tA[4] = {}, pA[4] = {};
    const size_t wrow = (size_t)(w * 16 + ml) * 64 + kq * 8;
#pragma unroll
    for (int kt = 0; kt < 2; kt++) {
      bf16x8 ath = *(const bf16x8*)(twh + wrow + kt * 32);
      bf16x8 atl = *(const bf16x8*)(twl + wrow + kt * 32);
      bf16x8 aph = *(const bf16x8*)(pwh + wrow + kt * 32);
      bf16x8 apl = *(const bf16x8*)(pwl + wrow + kt * 32);
      int kk = kt * 32 + kq * 8;
#pragma unroll
      for (int nt = 0; nt < 4; nt++) {
        bf16x8 bh = *(const bf16x8*)&NMh[XIDX(nt * 16 + ml, kk)];
        bf16x8 bl = *(const bf16x8*)&NMl[XIDX(nt * 16 + ml, kk)];
        tA[nt] = MFMA(ath, bh, tA[nt]);
        tA[nt] = MFMA(atl, bh, tA[nt]);
        tA[nt] = MFMA(ath, bl, tA[nt]);
        pA[nt] = MFMA(aph, bh, pA[nt]);
        pA[nt] = MFMA(apl, bh, pA[nt]);
        pA[nt] = MFMA(aph, bl, pA[nt]);
      }
    }
    // T -> LDS [node][ch] stride 68 (own-wave cols; wave-order write->read ok)
#pragma unroll
    for (int nt = 0; nt < 4; nt++) {
      int n = nt * 16 + ml;
      float4 tv;
      tv.x = tA[nt][0]; tv.y = tA[nt][1]; tv.z = tA[nt][2]; tv.w = tA[nt][3];
      *(float4*)&Tf[n * 68 + c0] = tv;
    }
    float4 tbv = *(const float4*)(tb + c0);
    float4 pbv = *(const float4*)(pb + c0);
#pragma unroll
    for (int nt = 0; nt < 4; nt++) {
      int n = nt * 16 + ml;
      unsigned w0 = sW[n * 4], w1 = sW[n * 4 + 1], w2 = sW[n * 4 + 2],
               w3 = sW[n * 4 + 3];
      float4 mn = {3.4e38f, 3.4e38f, 3.4e38f, 3.4e38f};
#pragma unroll
      for (int e = 0; e < 16; e++) {
        unsigned wd = (e < 4) ? w0 : (e < 8) ? w1 : (e < 12) ? w2 : w3;
        int s = (wd >> ((e & 3) * 8)) & 255;
        float4 tv = *(const float4*)&Tf[s * 68 + c0];
        mn.x = fminf(mn.x, tv.x); mn.y = fminf(mn.y, tv.y);
        mn.z = fminf(mn.z, tv.z); mn.w = fminf(mn.w, tv.w);
      }
      y[nt][0] = tA[nt][0] + pA[nt][0] + tbv.x + pbv.x - mn.x;
      y[nt][1] = tA[nt][1] + pA[nt][1] + tbv.y + pbv.y - mn.y;
      y[nt][2] = tA[nt][2] + pA[nt][2] + tbv.z + pbv.z - mn.z;
      y[nt][3] = tA[nt][3] + pA[nt][3] + tbv.w + pbv.w - mn.w;
    }
    stats_acc(so);
  };

  // ---- cheb layer 1 (feat input, FIN=16, K padded to 64) ----
  auto cheb1_graph = [&]() {
    {
      int n = t >> 2, cc = (t & 3) * 4;
      float4 v = *(const float4*)(p.feat + (size_t)(g * 64 + n) * 16 + cc);
      u16 hh[4], ll[4];
      split2(v.x, hh[0], ll[0]); split2(v.y, hh[1], ll[1]);
      split2(v.z, hh[2], ll[2]); split2(v.w, hh[3], ll[3]);
      s16x4 vh, vl;
#pragma unroll
      for (int i = 0; i < 4; i++) { vh[i] = (short)hh[i]; vl[i] = (short)ll[i]; }
      *(s16x4*)&NMh[XIDX(n, cc)] = vh;
      *(s16x4*)&NMl[XIDX(n, cc)] = vl;
#pragma unroll
      for (int i = 0; i < 4; i++) {
        CMh[XIDX(cc + i, n)] = hh[i];
        CMl[XIDX(cc + i, n)] = ll[i];
      }
    }
    if (w == 0) {
      bf16x8 z = {0, 0, 0, 0, 0, 0, 0, 0};
      *(bf16x8*)&NMh[XIDX(L, 48)] = z;
      *(bf16x8*)&NMh[XIDX(L, 56)] = z;
    } else if (w == 1) {
      bf16x8 z = {0, 0, 0, 0, 0, 0, 0, 0};
      *(bf16x8*)&NMl[XIDX(L, 48)] = z;
      *(bf16x8*)&NMl[XIDX(L, 56)] = z;
    } else if (w == 3) {
      build_adj(p.src, g, L, Adj);
    }
    __syncthreads();
    {  // lap1: X1 = -C1*Adj*X0 -> NM cols 16..31, CM rows 16..31 (disjoint)
      f32x4 l0 = {};
#pragma unroll
      for (int kt = 0; kt < 2; kt++) {
        int kk = kt * 32 + kq * 8;
        bf16x8 aa = *(const bf16x8*)&Adj[XIDX(w * 16 + ml, kk)];
        bf16x8 bh = *(const bf16x8*)&CMh[XIDX(ml, kk)];
        bf16x8 bl = *(const bf16x8*)&CMl[XIDX(ml, kk)];
        l0 = MFMA(aa, bh, l0);
        l0 = MFMA(aa, bl, l0);
      }
      int r0 = w * 16 + kq * 4;
      u16 hh[4], ll[4];
#pragma unroll
      for (int i = 0; i < 4; i++) {
        split2(l0[i] * (-C1), hh[i], ll[i]);
        NMh[XIDX(r0 + i, 16 + ml)] = hh[i];
        NMl[XIDX(r0 + i, 16 + ml)] = ll[i];
      }
      s16x4 vh, vl;
#pragma unroll
      for (int i = 0; i < 4; i++) { vh[i] = (short)hh[i]; vl[i] = (short)ll[i]; }
      *(s16x4*)&CMh[XIDX(16 + ml, r0)] = vh;
      *(s16x4*)&CMl[XIDX(16 + ml, r0)] = vl;
    }
    __syncthreads();
    {  // lap2: Z2 = -2C1*Adj*X1 -> NM cols 32..47
      f32x4 l0 = {};
#pragma unroll
      for (int kt = 0; kt < 2; kt++) {
        int kk = kt * 32 + kq * 8;
        bf16x8 aa = *(const bf16x8*)&Adj[XIDX(w * 16 + ml, kk)];
        bf16x8 bh = *(const bf16x8*)&CMh[XIDX(16 + ml, kk)];
        bf16x8 bl = *(const bf16x8*)&CMl[XIDX(16 + ml, kk)];
        l0 = MFMA(aa, bh, l0);
        l0 = MFMA(aa, bl, l0);
      }
      int r0 = w * 16 + kq * 4;
      u16 hh[4], ll[4];
#pragma unroll
      for (int i = 0; i < 4; i++) {
        split2(l0[i] * (-2.0f * C1), hh[i], ll[i]);
        NMh[XIDX(r0 + i, 32 + ml)] = hh[i];
        NMl[XIDX(r0 + i, 32 + ml)] = ll[i];
      }
    }
    __syncthreads();
    f32x4 acc[4] = {};
    const u16* whp = p.W1h + (size_t)(w * 16 + ml) * 64 + kq * 8;
    const u16* wlp = p.W1l + (size_t)(w * 16 + ml) * 64 + kq * 8;
#pragma unroll
    for (int kt = 0; kt < 2; kt++) {
      bf16x8 ah = *(const bf16x8*)(whp + kt * 32);
      bf16x8 al = *(const bf16x8*)(wlp + kt * 32);
      int kk = kt * 32 + kq * 8;
#pragma unroll
      for (int nt = 0; nt < 4; nt++) {
        bf16x8 bh = *(const bf16x8*)&NMh[XIDX(nt * 16 + ml, kk)];
        bf16x8 bl = *(const bf16x8*)&NMl[XIDX(nt * 16 + ml, kk)];
        acc[nt] = MFMA(ah, bh, acc[nt]);
        acc[nt] = MFMA(al, bh, acc[nt]);
        acc[nt] = MFMA(ah, bl, acc[nt]);
      }
    }
    float4 bb = *(const float4*)(p.c1b + c0);
#pragma unroll
    for (int nt = 0; nt < 4; nt++) {
      y[nt][0] = acc[nt][0] + bb.x;
      y[nt][1] = acc[nt][1] + bb.y;
      y[nt][2] = acc[nt][2] + bb.z;
      y[nt][3] = acc[nt][3] + bb.w;
    }
    stats_acc(p.stats);
  };

  // ---- final BN+ReLU + mean pool from frags (reg sc/sh) ----
  auto pool_graph = [&]() {
    float s[4] = {0, 0, 0, 0};
#pragma unroll
    for (int nt = 0; nt < 4; nt++)
#pragma unroll
      for (int i = 0; i < 4; i++)
        s[i] += fmaxf(fmaf(sc[i], y[nt][i], sh[i]), 0.f);
#pragma unroll
    for (int i = 0; i < 4; i++)
#pragma unroll
      for (int off = 1; off < 16; off <<= 1) s[i] += __shfl_xor(s[i], off, 64);
    if (ml == 0) {
      float4 o = make_float4(s[0] * (1.f / 64.f), s[1] * (1.f / 64.f),
                             s[2] * (1.f / 64.f), s[3] * (1.f / 64.f));
      *(float4*)(p.out + (size_t)g * 64 + c0) = o;
    }
  };

  // ======================= network =======================
  cheb1_graph();
  gbar(0);
  bn_coeffs(p.stats + 0, p.bn1g, p.bn1b);
  econv_graph(p.T1h, p.T1l, p.P1h, p.P1l, p.e1tb, p.e1pb,
              p.stats + (size_t)1 * NREP * 128);
  gbar(1);
  bn_coeffs(p.stats + (size_t)1 * NREP * 128, p.bne1g, p.bne1b);
  cheb64_graph(p.W2h, p.W2l, p.c2b, p.stats + (size_t)2 * NREP * 128);
  gbar(2);
  bn_coeffs(p.stats + (size_t)2 * NREP * 128, p.bn2g, p.bn2b);
  econv_graph(p.T2h, p.T2l, p.P2h, p.P2l, p.e2tb, p.e2pb,
              p.stats + (size_t)3 * NREP * 128);
  gbar(3);
  bn_coeffs(p.stats + (size_t)3 * NREP * 128, p.bne2g, p.bne2b);
  cheb64_graph(p.W3h, p.W3l, p.c3b, p.stats + (size_t)4 * NREP * 128);
  gbar(4);
  bn_coeffs(p.stats + (size_t)4 * NREP * 128, p.bn3g, p.bn3b);
  pool_graph();
}

// ---------------------------------------------------------------------------
// Weight prep: fold recurrence, pad, split to bf16 hi/lo; zero replica stats
// and barrier counters. Own dispatch -> kernel-boundary flush publishes
// everything coherently to all XCDs before k_fused.
// ---------------------------------------------------------------------------
__global__ void k_prep(const float* __restrict__ c1w, const float* __restrict__ c2w,
                       const float* __restrict__ c3w, const float* __restrict__ e1t,
                       const float* __restrict__ e1p, const float* __restrict__ e2t,
                       const float* __restrict__ e2p, u16* __restrict__ W1h,
                       u16* __restrict__ W1l, u16* __restrict__ W2h,
                       u16* __restrict__ W2l, u16* __restrict__ W3h,
                       u16* __restrict__ W3l, u16* __restrict__ T1h,
                       u16* __restrict__ T1l, u16* __restrict__ P1h,
                       u16* __restrict__ P1l, u16* __restrict__ T2h,
                       u16* __restrict__ T2l, u16* __restrict__ P2h,
                       u16* __restrict__ P2l, float* __restrict__ stats,
                       unsigned* __restrict__ bar) {
  int t0 = blockIdx.x * 256 + threadIdx.x;
  int stride = gridDim.x * 256;
  for (int i = t0; i < 5 * NREP * 128; i += stride) stats[i] = 0.f;
  if (t0 < 8) bar[t0] = 0u;
  for (int i = t0; i < 4096; i += stride) {
    int r = i >> 6, c = i & 63;
    float v = 0.f;
    if (c < 16) v = c1w[r * 48 + c] - c1w[r * 48 + 32 + c];
    else if (c < 48) v = c1w[r * 48 + c];
    u16 h, l; split2(v, h, l); W1h[i] = h; W1l[i] = l;
  }
  for (int i = t0; i < 12288; i += stride) {
    int r = i / 192, c = i - r * 192;
    float v = (c < 64) ? c2w[r * 192 + c] - c2w[r * 192 + 128 + c]
                       : c2w[r * 192 + c];
    u16 h, l; split2(v, h, l); W2h[i] = h; W2l[i] = l;
  }
  for (int i = t0; i < 12288; i += stride) {
    int r = i / 192, c = i - r * 192;
    float v = (c < 64) ? c3w[r * 192 + c] - c3w[r * 192 + 128 + c]
                       : c3w[r * 192 + c];
    u16 h, l; split2(v, h, l); W3h[i] = h; W3l[i] = l;
  }
  for (int i = t0; i < 4096; i += stride) {
    u16 h, l;
    split2(e1t[i], h, l); T1h[i] = h; T1l[i] = l;
    split2(e1p[i], h, l); P1h[i] = h; P1l[i] = l;
    split2(e2t[i], h, l); T2h[i] = h; T2l[i] = l;
    split2(e2p[i], h, l); P2h[i] = h; P2l[i] = l;
  }
}

// ---------------------------------------------------------------------------
extern "C" void kernel_launch(void* const* d_in, const int* in_sizes, int n_in,
                              void* d_out, int out_size, void* d_ws,
                              size_t ws_size, hipStream_t stream) {
  const float* feat = (const float*)d_in[0];
  const int* src = (const int*)d_in[1];
  const float* cheb1_w = (const float*)d_in[4];
  const float* cheb1_b = (const float*)d_in[5];
  const float* bn1_g = (const float*)d_in[6];
  const float* bn1_b = (const float*)d_in[7];
  const float* e1_tw = (const float*)d_in[8];
  const float* e1_tb = (const float*)d_in[9];
  const float* e1_pw = (const float*)d_in[10];
  const float* e1_pb = (const float*)d_in[11];
  const float* bne1_g = (const float*)d_in[12];
  const float* bne1_b = (const float*)d_in[13];
  const float* cheb2_w = (const float*)d_in[14];
  const float* cheb2_b = (const float*)d_in[15];
  const float* bn2_g = (const float*)d_in[16];
  const float* bn2_b = (const float*)d_in[17];
  const float* e2_tw = (const float*)d_in[18];
  const float* e2_tb = (const float*)d_in[19];
  const float* e2_pw = (const float*)d_in[20];
  const float* e2_pb = (const float*)d_in[21];
  const float* bne2_g = (const float*)d_in[22];
  const float* bne2_b = (const float*)d_in[23];
  const float* cheb3_w = (const float*)d_in[24];
  const float* cheb3_b = (const float*)d_in[25];
  const float* bn3_g = (const float*)d_in[26];
  const float* bn3_b = (const float*)d_in[27];

  float* stats = (float*)d_ws;  // 5 x NREP x 128 replica stats
  unsigned* bar = (unsigned*)(stats + 5 * NREP * 128);  // 8 barrier counters
  u16* wq = (u16*)(bar + 8);
  u16* W1h = wq;           u16* W1l = W1h + 4096;
  u16* W2h = W1l + 4096;   u16* W2l = W2h + 12288;
  u16* W3h = W2l + 12288;  u16* W3l = W3h + 12288;
  u16* T1h = W3l + 12288;  u16* T1l = T1h + 4096;
  u16* P1h = T1l + 4096;   u16* P1l = P1h + 4096;
  u16* T2h = P1l + 4096;   u16* T2l = T2h + 4096;
  u16* P2h = T2l + 4096;   u16* P2l = P2h + 4096;

  k_prep<<<16, 256, 0, stream>>>(cheb1_w, cheb2_w, cheb3_w, e1_tw, e1_pw,
                                 e2_tw, e2_pw, W1h, W1l, W2h, W2l, W3h, W3l,
                                 T1h, T1l, P1h, P1l, T2h, T2l, P2h, P2l,
                                 stats, bar);

  KP p;
  p.feat = feat; p.src = src;
  p.W1h = W1h; p.W1l = W1l; p.W2h = W2h; p.W2l = W2l; p.W3h = W3h; p.W3l = W3l;
  p.T1h = T1h; p.T1l = T1l; p.P1h = P1h; p.P1l = P1l;
  p.T2h = T2h; p.T2l = T2l; p.P2h = P2h; p.P2l = P2l;
  p.c1b = cheb1_b; p.bn1g = bn1_g; p.bn1b = bn1_b;
  p.e1tb = e1_tb; p.e1pb = e1_pb; p.bne1g = bne1_g; p.bne1b = bne1_b;
  p.c2b = cheb2_b; p.bn2g = bn2_g; p.bn2b = bn2_b;
  p.e2tb = e2_tb; p.e2pb = e2_pb; p.bne2g = bne2_g; p.bne2b = bne2_b;
  p.c3b = cheb3_b; p.bn3g = bn3_g; p.bn3b = bn3_b;
  p.stats = stats; p.bar = bar; p.out = (float*)d_out;

  // 1024 blocks @ __launch_bounds__(256,4), LDS 40960 B -> exactly 4
  // blocks/CU on 256 CUs, all resident (exclusive GPU); relaxed barrier.
  k_fused<<<NBLK, 256, 0, stream>>>(p);
}

// Round 7
// 209.303 us; speedup vs baseline: 1.7590x; 1.7590x over previous
//
#include <hip/hip_runtime.h>

#define NN 65536
#define PP 64
#define HH 64
#define FINN 16
#define NG 1024
#define EPSF 1e-5f
#define C1 0.0625f
#define NREP 32  // stats accumulator replicas (contention spread)

typedef short bf16x8 __attribute__((ext_vector_type(8)));
typedef short s16x4 __attribute__((ext_vector_type(4)));
typedef float f32x4 __attribute__((ext_vector_type(4)));
typedef unsigned short u16;

#define MFMA(a, b, c) __builtin_amdgcn_mfma_f32_16x16x32_bf16(a, b, c, 0, 0, 0)

__device__ __forceinline__ u16 f2bf(float x) {
  union { float f; unsigned u; } v; v.f = x; return (u16)(v.u >> 16);
}
__device__ __forceinline__ float bf2f(u16 h) {
  union { float f; unsigned u; } v; v.u = ((unsigned)h) << 16; return v.f;
}
__device__ __forceinline__ void split2(float x, u16& h, u16& l) {
  h = f2bf(x); l = f2bf(x - bf2f(h));
}
// swizzled index into a 64x64 u16 LDS tile: 16B granules XOR'd by row&7
__device__ __forceinline__ int XIDX(int r, int c) {
  return r * 64 + ((((c >> 3) ^ (r & 7)) << 3) | (c & 7));
}

// Build local adjacency (multiplicity) for this graph into Adj (bf16, swizzled).
__device__ __forceinline__ void build_adj(const int* __restrict__ src, int g,
                                          int r, u16* Adj) {
  bf16x8 z = {0, 0, 0, 0, 0, 0, 0, 0};
#pragma unroll
  for (int q = 0; q < 8; q++) *(bf16x8*)&Adj[r * 64 + q * 8] = z;
  const int4* s4 = (const int4*)(src + (size_t)g * 1024 + (size_t)r * 16);
  int4 a0 = s4[0], a1 = s4[1], a2 = s4[2], a3 = s4[3];
  int b0 = g * 64;
  int ss[16] = {a0.x - b0, a0.y - b0, a0.z - b0, a0.w - b0,
                a1.x - b0, a1.y - b0, a1.z - b0, a1.w - b0,
                a2.x - b0, a2.y - b0, a2.z - b0, a2.w - b0,
                a3.x - b0, a3.y - b0, a3.z - b0, a3.w - b0};
#pragma unroll
  for (int e = 0; e < 16; e++) {
    int idx = XIDX(r, ss[e]);
    Adj[idx] = f2bf(bf2f(Adj[idx]) + 1.0f);
  }
}

// Sum the 32 replica rows of this boundary's stats into LDS sstats[128].
// Plain loads: kernel-boundary flush makes prior kernel's atomics coherent.
__device__ __forceinline__ void rep_reduce(const float* __restrict__ stats_in,
                                           int t, float* sstats) {
  if (t < 128) {
    float s = 0.f;
    const float* p = stats_in + t;
#pragma unroll
    for (int r = 0; r < NREP; r++) s += p[r * 128];
    sstats[t] = s;
  }
}

// Phase 1 of BN-staging ([node:t>>2, 16ch] mapping, used by econv/pool).
__device__ __forceinline__ void stage_load(const float* __restrict__ y_in,
                                           int g, int t, float4* v) {
  int n = t >> 2, c0 = (t & 3) * 16;
  const float* yr = y_in + ((size_t)(g * 64 + n)) * 64 + c0;
#pragma unroll
  for (int q = 0; q < 4; q++) v[q] = ((const float4*)yr)[q];
}

// Phase 2: BN+ReLU from regs using LDS sstats -> node-major split-bf16 tiles.
__device__ __forceinline__ void stage_bn2(
    const float4* v, const float* sstats, const float* __restrict__ gam,
    const float* __restrict__ bet, int t, u16* NMh, u16* NMl) {
  const float inv = 1.0f / (float)NN;
  int n = t >> 2, c0 = (t & 3) * 16;
  u16 hh[16], ll[16];
#pragma unroll
  for (int q = 0; q < 4; q++) {
#pragma unroll
    for (int k = 0; k < 4; k++) {
      int c = c0 + q * 4 + k;
      float s1 = sstats[c], s2 = sstats[64 + c];
      float mu = s1 * inv;
      float var = fmaf(s2, inv, -mu * mu);
      float sc = gam[c] * rsqrtf(var + EPSF);
      float sh = fmaf(-mu, sc, bet[c]);
      float x = (k == 0) ? v[q].x : (k == 1) ? v[q].y : (k == 2) ? v[q].z
                                                                 : v[q].w;
      float h = fmaxf(fmaf(sc, x, sh), 0.f);
      split2(h, hh[q * 4 + k], ll[q * 4 + k]);
    }
  }
  bf16x8 vh0, vh1, vl0, vl1;
#pragma unroll
  for (int k = 0; k < 8; k++) {
    vh0[k] = (short)hh[k]; vl0[k] = (short)ll[k];
    vh1[k] = (short)hh[8 + k]; vl1[k] = (short)ll[8 + k];
  }
  *(bf16x8*)&NMh[XIDX(n, c0)] = vh0;
  *(bf16x8*)&NMh[XIDX(n, c0 + 8)] = vh1;
  *(bf16x8*)&NMl[XIDX(n, c0)] = vl0;
  *(bf16x8*)&NMl[XIDX(n, c0 + 8)] = vl1;
}

// Epilogue: add bias, store y frags, atomicAdd BN partials to replica g&31.
__device__ __forceinline__ void epilogue(f32x4 a0, f32x4 a1, f32x4 a2, f32x4 a3,
                                         const float* __restrict__ bias, int g,
                                         int w, int ml, int kq,
                                         float* __restrict__ y_out,
                                         float* __restrict__ stats_out) {
  float4 bb = *(const float4*)(bias + w * 16 + kq * 4);
  float s1[4] = {0, 0, 0, 0}, s2[4] = {0, 0, 0, 0};
#pragma unroll
  for (int nt = 0; nt < 4; nt++) {
    f32x4 A = (nt == 0) ? a0 : (nt == 1) ? a1 : (nt == 2) ? a2 : a3;
    float4 yv;
    yv.x = A[0] + bb.x; yv.y = A[1] + bb.y;
    yv.z = A[2] + bb.z; yv.w = A[3] + bb.w;
    int n = nt * 16 + ml;
    *(float4*)(y_out + ((size_t)(g * 64 + n)) * 64 + w * 16 + kq * 4) = yv;
    s1[0] += yv.x; s2[0] += yv.x * yv.x;
    s1[1] += yv.y; s2[1] += yv.y * yv.y;
    s1[2] += yv.z; s2[2] += yv.z * yv.z;
    s1[3] += yv.w; s2[3] += yv.w * yv.w;
  }
#pragma unroll
  for (int i = 0; i < 4; i++) {
#pragma unroll
    for (int off = 1; off < 16; off <<= 1) {
      s1[i] += __shfl_xor(s1[i], off, 64);
      s2[i] += __shfl_xor(s2[i], off, 64);
    }
  }
  if (ml == 0) {
    float* pr = stats_out + (size_t)(g & (NREP - 1)) * 128 + w * 16 + kq * 4;
    atomicAdd(pr + 0, s1[0]);
    atomicAdd(pr + 1, s1[1]);
    atomicAdd(pr + 2, s1[2]);
    atomicAdd(pr + 3, s1[3]);
    atomicAdd(pr + 64, s2[0]);
    atomicAdd(pr + 65, s2[1]);
    atomicAdd(pr + 66, s2[2]);
    atomicAdd(pr + 67, s2[3]);
  }
}

// ---------------------------------------------------------------------------
// cheb layer, CI=64 (layers 3 & 5). W folded: [W0-W2 | W1 | W2], K=192.
// v2: LDS cut 57344 -> 40960 B (round-6-verified in-place col-major reuse)
// -> 4 blocks/CU (was 2; round-1 occupancy was 14%). Frag-mapped y loads +
// graph-invariant reg sc/sh (4 rsqrtf/thread); sstats aliases Adj head.
// ---------------------------------------------------------------------------
__global__ __launch_bounds__(256, 4) void k_cheb64(
    const float* __restrict__ y_in, const float* __restrict__ stats_in,
    const float* __restrict__ gam, const float* __restrict__ bet,
    const int* __restrict__ src, const u16* __restrict__ wh,
    const u16* __restrict__ wl, const float* __restrict__ bias,
    float* __restrict__ y_out, float* __restrict__ stats_out) {
  __shared__ __align__(16) u16 SH[20480];  // 40960 B exactly
  u16* NMh = SH;
  u16* NMl = SH + 4096;
  u16* CMh = SH + 8192;
  u16* CMl = SH + 12288;
  u16* Adj = SH + 16384;
  float* sstats = (float*)(SH + 16384);  // transient over Adj head

  const int t = threadIdx.x, g = blockIdx.x;
  const int L = t & 63;
  const int w = __builtin_amdgcn_readfirstlane(t >> 6);
  const int ml = L & 15, kq = L >> 4;
  const int c0 = w * 16 + kq * 4;

  // frag-mapped y loads (early issue, overlap with rep_reduce)
  float4 yv[4];
#pragma unroll
  for (int nt = 0; nt < 4; nt++)
    yv[nt] =
        *(const float4*)(y_in + ((size_t)(g * 64 + nt * 16 + ml)) * 64 + c0);
  rep_reduce(stats_in, t, sstats);
  __syncthreads();
  float sc[4], sh[4];
  {
    const float inv = 1.0f / (float)NN;
#pragma unroll
    for (int i = 0; i < 4; i++) {
      int c = c0 + i;
      float s1 = sstats[c], s2 = sstats[64 + c];
      float mu = s1 * inv;
      float var = fmaf(s2, inv, -mu * mu);
      sc[i] = gam[c] * rsqrtf(var + EPSF);
      sh[i] = fmaf(-mu, sc[i], bet[c]);
    }
  }
  __syncthreads();  // sstats consumed; Adj may overwrite

  // BN+ReLU -> NM + CM tiles; wave 3 also builds Adj
#pragma unroll
  for (int nt = 0; nt < 4; nt++) {
    int node = nt * 16 + ml;
    u16 hh[4], ll[4];
    s16x4 vh, vl;
    float xs[4] = {yv[nt].x, yv[nt].y, yv[nt].z, yv[nt].w};
#pragma unroll
    for (int i = 0; i < 4; i++) {
      float h = fmaxf(fmaf(sc[i], xs[i], sh[i]), 0.f);
      split2(h, hh[i], ll[i]);
      vh[i] = (short)hh[i]; vl[i] = (short)ll[i];
    }
    *(s16x4*)&NMh[XIDX(node, c0)] = vh;
    *(s16x4*)&NMl[XIDX(node, c0)] = vl;
#pragma unroll
    for (int i = 0; i < 4; i++) {
      CMh[XIDX(c0 + i, node)] = hh[i];
      CMl[XIDX(c0 + i, node)] = ll[i];
    }
  }
  if (w == 3) build_adj(src, g, L, Adj);
  __syncthreads();

  f32x4 acc[4] = {};
  const u16* whp = wh + (size_t)(w * 16 + ml) * 192 + kq * 8;
  const u16* wlp = wl + (size_t)(w * 16 + ml) * 192 + kq * 8;

  auto yacc = [&](int kbase) {
#pragma unroll
    for (int kt = 0; kt < 2; kt++) {
      bf16x8 ah = *(const bf16x8*)(whp + kbase + kt * 32);
      bf16x8 al = *(const bf16x8*)(wlp + kbase + kt * 32);
      int kk = kt * 32 + kq * 8;
#pragma unroll
      for (int nt = 0; nt < 4; nt++) {
        bf16x8 bh = *(const bf16x8*)&NMh[XIDX(nt * 16 + ml, kk)];
        bf16x8 bl = *(const bf16x8*)&NMl[XIDX(nt * 16 + ml, kk)];
        acc[nt] = MFMA(ah, bh, acc[nt]);
        acc[nt] = MFMA(al, bh, acc[nt]);
        acc[nt] = MFMA(ah, bl, acc[nt]);
      }
    }
  };
  // lap: L = Adj * X (X col-major from CM). Writes node-major into NM and,
  // if writeCM, col-major IN PLACE over CM (in-lap sync separates the WAR).
  auto lap = [&](float scale, bool writeCM) {
    f32x4 l[4] = {};
#pragma unroll
    for (int kt = 0; kt < 2; kt++) {
      int kk = kt * 32 + kq * 8;
      bf16x8 aa = *(const bf16x8*)&Adj[XIDX(w * 16 + ml, kk)];
#pragma unroll
      for (int nt = 0; nt < 4; nt++) {
        bf16x8 bh = *(const bf16x8*)&CMh[XIDX(nt * 16 + ml, kk)];
        bf16x8 bl = *(const bf16x8*)&CMl[XIDX(nt * 16 + ml, kk)];
        l[nt] = MFMA(aa, bh, l[nt]);
        l[nt] = MFMA(aa, bl, l[nt]);
      }
    }
    if (writeCM) __syncthreads();  // WAR: CM writes below vs CM reads above
    int r0 = w * 16 + kq * 4;
#pragma unroll
    for (int nt = 0; nt < 4; nt++) {
      int c = nt * 16 + ml;
      u16 hh[4], ll[4];
#pragma unroll
      for (int i = 0; i < 4; i++) {
        split2(l[nt][i] * scale, hh[i], ll[i]);
        NMh[XIDX(r0 + i, c)] = hh[i];
        NMl[XIDX(r0 + i, c)] = ll[i];
      }
      if (writeCM) {
        s16x4 vh, vl;
#pragma unroll
        for (int i = 0; i < 4; i++) { vh[i] = (short)hh[i]; vl[i] = (short)ll[i]; }
        *(s16x4*)&CMh[XIDX(c, r0)] = vh;
        *(s16x4*)&CMl[XIDX(c, r0)] = vl;
      }
    }
  };

  yacc(0);                  // X0 vs W0' = W0 - W2
  __syncthreads();
  lap(-C1, true);           // X1 = -C1*Adj*X0 -> NM + CM (in place)
  __syncthreads();
  yacc(64);                 // X1 vs W1
  __syncthreads();
  lap(-2.0f * C1, false);   // Z2 = -2C1*Adj*X1 -> NM
  __syncthreads();
  yacc(128);                // Z2 vs W2
  epilogue(acc[0], acc[1], acc[2], acc[3], bias, g, w, ml, kq, y_out,
           stats_out);
}

// ---------------------------------------------------------------------------
// econv: y[n] = T[n] + P[n] + tb + pb - min_src T[src]   (round-2 verified)
// ---------------------------------------------------------------------------
__global__ __launch_bounds__(256, 4) void k_econv(
    const float* __restrict__ y_in, const float* __restrict__ stats_in,
    const float* __restrict__ gam, const float* __restrict__ bet,
    const int* __restrict__ src, const u16* __restrict__ twh,
    const u16* __restrict__ twl, const u16* __restrict__ pwh,
    const u16* __restrict__ pwl, const float* __restrict__ tb,
    const float* __restrict__ pb, float* __restrict__ y_out,
    float* __restrict__ stats_out) {
  __shared__ u16 NMh[4096], NMl[4096];
  __shared__ float Tf[64 * 68];
  __shared__ unsigned sW[256];
  __shared__ float sstats[128];
  const int t = threadIdx.x, g = blockIdx.x;
  const int L = t & 63;
  const int w = __builtin_amdgcn_readfirstlane(t >> 6);
  const int ml = L & 15, kq = L >> 4;

  float4 yv4[4];
  stage_load(y_in, g, t, yv4);
  {
    const int4* s4 = (const int4*)(src + (size_t)g * 1024);
    int4 v = s4[t];
    int b0 = g * 64;
    sW[t] = (unsigned)(v.x - b0) | ((unsigned)(v.y - b0) << 8) |
            ((unsigned)(v.z - b0) << 16) | ((unsigned)(v.w - b0) << 24);
  }
  rep_reduce(stats_in, t, sstats);
  __syncthreads();
  stage_bn2(yv4, sstats, gam, bet, t, NMh, NMl);
  __syncthreads();

  f32x4 t0 = {0,0,0,0}, t1 = {0,0,0,0}, t2 = {0,0,0,0}, t3 = {0,0,0,0};
  f32x4 p0 = {0,0,0,0}, p1 = {0,0,0,0}, p2 = {0,0,0,0}, p3 = {0,0,0,0};
  const size_t wrow = (size_t)(w * 16 + ml) * 64 + kq * 8;
#pragma unroll
  for (int kt = 0; kt < 2; kt++) {
    bf16x8 ath = *(const bf16x8*)(twh + wrow + kt * 32);
    bf16x8 atl = *(const bf16x8*)(twl + wrow + kt * 32);
    bf16x8 aph = *(const bf16x8*)(pwh + wrow + kt * 32);
    bf16x8 apl = *(const bf16x8*)(pwl + wrow + kt * 32);
    int kk = kt * 32 + kq * 8;
#pragma unroll
    for (int nt = 0; nt < 4; nt++) {
      int node = nt * 16 + ml;
      bf16x8 bh = *(const bf16x8*)&NMh[XIDX(node, kk)];
      bf16x8 bl = *(const bf16x8*)&NMl[XIDX(node, kk)];
      f32x4& T = (nt == 0) ? t0 : (nt == 1) ? t1 : (nt == 2) ? t2 : t3;
      f32x4& P = (nt == 0) ? p0 : (nt == 1) ? p1 : (nt == 2) ? p2 : p3;
      T = MFMA(ath, bh, T); T = MFMA(atl, bh, T); T = MFMA(ath, bl, T);
      P = MFMA(aph, bh, P); P = MFMA(apl, bh, P); P = MFMA(aph, bl, P);
    }
  }
  // write T to LDS [node][ch], stride 68 (own-wave columns only)
#pragma unroll
  for (int nt = 0; nt < 4; nt++) {
    f32x4 T = (nt == 0) ? t0 : (nt == 1) ? t1 : (nt == 2) ? t2 : t3;
    int n = nt * 16 + ml;
    float4 v; v.x = T[0]; v.y = T[1]; v.z = T[2]; v.w = T[3];
    *(float4*)&Tf[n * 68 + w * 16 + kq * 4] = v;
  }
  // min-gather + epilogue (Tf rows all written by this wave; sW synced above)
  float4 tbv = *(const float4*)(tb + w * 16 + kq * 4);
  float4 pbv = *(const float4*)(pb + w * 16 + kq * 4);
  float s1[4] = {0, 0, 0, 0}, s2[4] = {0, 0, 0, 0};
#pragma unroll
  for (int nt = 0; nt < 4; nt++) {
    int n = nt * 16 + ml;
    unsigned w0 = sW[n * 4], w1 = sW[n * 4 + 1], w2 = sW[n * 4 + 2],
             w3 = sW[n * 4 + 3];
    float4 mn = {3.4e38f, 3.4e38f, 3.4e38f, 3.4e38f};
#pragma unroll
    for (int e = 0; e < 16; e++) {
      unsigned wd = (e < 4) ? w0 : (e < 8) ? w1 : (e < 12) ? w2 : w3;
      int s = (wd >> ((e & 3) * 8)) & 255;
      float4 tv = *(const float4*)&Tf[s * 68 + w * 16 + kq * 4];
      mn.x = fminf(mn.x, tv.x); mn.y = fminf(mn.y, tv.y);
      mn.z = fminf(mn.z, tv.z); mn.w = fminf(mn.w, tv.w);
    }
    f32x4 T = (nt == 0) ? t0 : (nt == 1) ? t1 : (nt == 2) ? t2 : t3;
    f32x4 P = (nt == 0) ? p0 : (nt == 1) ? p1 : (nt == 2) ? p2 : p3;
    float4 yv;
    yv.x = T[0] + P[0] + tbv.x + pbv.x - mn.x;
    yv.y = T[1] + P[1] + tbv.y + pbv.y - mn.y;
    yv.z = T[2] + P[2] + tbv.z + pbv.z - mn.z;
    yv.w = T[3] + P[3] + tbv.w + pbv.w - mn.w;
    *(float4*)(y_out + ((size_t)(g * 64 + n)) * 64 + w * 16 + kq * 4) = yv;
    s1[0] += yv.x; s2[0] += yv.x * yv.x;
    s1[1] += yv.y; s2[1] += yv.y * yv.y;
    s1[2] += yv.z; s2[2] += yv.z * yv.z;
    s1[3] += yv.w; s2[3] += yv.w * yv.w;
  }
#pragma unroll
  for (int i = 0; i < 4; i++) {
#pragma unroll
    for (int off = 1; off < 16; off <<= 1) {
      s1[i] += __shfl_xor(s1[i], off, 64);
      s2[i] += __shfl_xor(s2[i], off, 64);
    }
  }
  if (ml == 0) {
    float* pr = stats_out + (size_t)(g & (NREP - 1)) * 128 + w * 16 + kq * 4;
    atomicAdd(pr + 0, s1[0]);
    atomicAdd(pr + 1, s1[1]);
    atomicAdd(pr + 2, s1[2]);
    atomicAdd(pr + 3, s1[3]);
    atomicAdd(pr + 64, s2[0]);
    atomicAdd(pr + 65, s2[1]);
    atomicAdd(pr + 66, s2[2]);
    atomicAdd(pr + 67, s2[3]);
  }
}

// ---------------------------------------------------------------------------
// cheb layer 1: input feat (FIN=16), X-concat padded to K=64. LDS is already
// 40960 B (5 tiles) -> bump to 4 blocks/CU (was 3).
// ---------------------------------------------------------------------------
__global__ __launch_bounds__(256, 4) void k_cheb1(
    const float* __restrict__ feat, const int* __restrict__ src,
    const u16* __restrict__ wh, const u16* __restrict__ wl,
    const float* __restrict__ bias, float* __restrict__ y_out,
    float* __restrict__ stats_out) {
  __shared__ u16 NMh[4096], NMl[4096], Ch[4096], Cl[4096], Adj[4096];
  const int t = threadIdx.x, g = blockIdx.x;
  const int L = t & 63;
  const int w = __builtin_amdgcn_readfirstlane(t >> 6);
  const int ml = L & 15, kq = L >> 4;
  {  // stage X0 = feat: thread covers node t>>2, ch (t&3)*4..+3
    int n = t >> 2, c0 = (t & 3) * 4;
    float4 v = *(const float4*)(feat + (size_t)(g * 64 + n) * 16 + c0);
    u16 hh[4], ll[4];
    split2(v.x, hh[0], ll[0]); split2(v.y, hh[1], ll[1]);
    split2(v.z, hh[2], ll[2]); split2(v.w, hh[3], ll[3]);
    s16x4 vh, vl;
#pragma unroll
    for (int i = 0; i < 4; i++) { vh[i] = (short)hh[i]; vl[i] = (short)ll[i]; }
    *(s16x4*)&NMh[XIDX(n, c0)] = vh;
    *(s16x4*)&NMl[XIDX(n, c0)] = vl;
#pragma unroll
    for (int i = 0; i < 4; i++) {
      Ch[XIDX(c0 + i, n)] = hh[i];
      Cl[XIDX(c0 + i, n)] = ll[i];
    }
  }
  // zero NM pad cols 48..63; build Adj
  if (w == 0) {
    bf16x8 z = {0, 0, 0, 0, 0, 0, 0, 0};
    *(bf16x8*)&NMh[XIDX(L, 48)] = z;
    *(bf16x8*)&NMh[XIDX(L, 56)] = z;
  } else if (w == 1) {
    bf16x8 z = {0, 0, 0, 0, 0, 0, 0, 0};
    *(bf16x8*)&NMl[XIDX(L, 48)] = z;
    *(bf16x8*)&NMl[XIDX(L, 56)] = z;
  } else if (w == 3) {
    build_adj(src, g, L, Adj);
  }
  __syncthreads();

  // lap1: X1 = -C1*Adj*X0 (ch 0..15) -> NM cols 16..31, CM rows 16..31
  {
    f32x4 l0 = {0, 0, 0, 0};
#pragma unroll
    for (int kt = 0; kt < 2; kt++) {
      int kk = kt * 32 + kq * 8;
      bf16x8 aa = *(const bf16x8*)&Adj[XIDX(w * 16 + ml, kk)];
      bf16x8 bh = *(const bf16x8*)&Ch[XIDX(ml, kk)];
      bf16x8 bl = *(const bf16x8*)&Cl[XIDX(ml, kk)];
      l0 = MFMA(aa, bh, l0);
      l0 = MFMA(aa, bl, l0);
    }
    int r0 = w * 16 + kq * 4;
    u16 hh[4], ll[4];
#pragma unroll
    for (int i = 0; i < 4; i++) {
      split2(l0[i] * (-C1), hh[i], ll[i]);
      NMh[XIDX(r0 + i, 16 + ml)] = hh[i];
      NMl[XIDX(r0 + i, 16 + ml)] = ll[i];
    }
    s16x4 vh, vl;
#pragma unroll
    for (int i = 0; i < 4; i++) { vh[i] = (short)hh[i]; vl[i] = (short)ll[i]; }
    *(s16x4*)&Ch[XIDX(16 + ml, r0)] = vh;
    *(s16x4*)&Cl[XIDX(16 + ml, r0)] = vl;
  }
  __syncthreads();
  // lap2: Z2 = -2C1*Adj*X1 -> NM cols 32..47
  {
    f32x4 l0 = {0, 0, 0, 0};
#pragma unroll
    for (int kt = 0; kt < 2; kt++) {
      int kk = kt * 32 + kq * 8;
      bf16x8 aa = *(const bf16x8*)&Adj[XIDX(w * 16 + ml, kk)];
      bf16x8 bh = *(const bf16x8*)&Ch[XIDX(16 + ml, kk)];
      bf16x8 bl = *(const bf16x8*)&Cl[XIDX(16 + ml, kk)];
      l0 = MFMA(aa, bh, l0);
      l0 = MFMA(aa, bl, l0);
    }
    int r0 = w * 16 + kq * 4;
    u16 hh[4], ll[4];
#pragma unroll
    for (int i = 0; i < 4; i++) {
      split2(l0[i] * (-2.0f * C1), hh[i], ll[i]);
      NMh[XIDX(r0 + i, 32 + ml)] = hh[i];
      NMl[XIDX(r0 + i, 32 + ml)] = ll[i];
    }
  }
  __syncthreads();
  // Y = Xcat @ Wfold^T, K=64
  f32x4 acc0 = {0,0,0,0}, acc1 = {0,0,0,0}, acc2 = {0,0,0,0}, acc3 = {0,0,0,0};
  const u16* whp = wh + (size_t)(w * 16 + ml) * 64 + kq * 8;
  const u16* wlp = wl + (size_t)(w * 16 + ml) * 64 + kq * 8;
#pragma unroll
  for (int kt = 0; kt < 2; kt++) {
    bf16x8 ah = *(const bf16x8*)(whp + kt * 32);
    bf16x8 al = *(const bf16x8*)(wlp + kt * 32);
    int kk = kt * 32 + kq * 8;
#pragma unroll
    for (int nt = 0; nt < 4; nt++) {
      int node = nt * 16 + ml;
      bf16x8 bh = *(const bf16x8*)&NMh[XIDX(node, kk)];
      bf16x8 bl = *(const bf16x8*)&NMl[XIDX(node, kk)];
      f32x4& A = (nt == 0) ? acc0 : (nt == 1) ? acc1 : (nt == 2) ? acc2 : acc3;
      A = MFMA(ah, bh, A);
      A = MFMA(al, bh, A);
      A = MFMA(ah, bl, A);
    }
  }
  epilogue(acc0, acc1, acc2, acc3, bias, g, w, ml, kq, y_out, stats_out);
}

// ---------------------------------------------------------------------------
// Final BN+ReLU + mean-pool (replica-reduces its own stats)
// ---------------------------------------------------------------------------
__global__ __launch_bounds__(256, 4) void k_pool(
    const float* __restrict__ y_in, const float* __restrict__ stats_in,
    const float* __restrict__ gam, const float* __restrict__ bet,
    float* __restrict__ out) {
  __shared__ float sstats[128];
  int t = threadIdx.x, g = blockIdx.x;
  int n = t & 63;
  int cog = __builtin_amdgcn_readfirstlane(t >> 6);
  const float inv = 1.0f / (float)NN;
  const float* yr = y_in + ((size_t)(g * 64 + n)) * 64 + cog * 16;
  float4 v[4];
#pragma unroll
  for (int q = 0; q < 4; q++) v[q] = ((const float4*)yr)[q];
  rep_reduce(stats_in, t, sstats);
  __syncthreads();
  float sumv = 0.f;
#pragma unroll
  for (int q = 0; q < 4; q++) {
#pragma unroll
    for (int k = 0; k < 4; k++) {
      int j = q * 4 + k;
      int c = cog * 16 + j;
      float s1 = sstats[c], s2 = sstats[64 + c];
      float mu = s1 * inv;
      float var = fmaf(s2, inv, -mu * mu);
      float sc = gam[c] * rsqrtf(var + EPSF);
      float sh = fmaf(-mu, sc, bet[c]);
      float x = (k == 0) ? v[q].x : (k == 1) ? v[q].y : (k == 2) ? v[q].z
                                                                 : v[q].w;
      float h = fmaxf(fmaf(sc, x, sh), 0.f);
      float s = h;
#pragma unroll
      for (int off = 32; off >= 1; off >>= 1) s += __shfl_xor(s, off, 64);
      sumv = (n == j) ? s : sumv;
    }
  }
  if (n < 16) out[(size_t)g * 64 + cog * 16 + n] = sumv * (1.0f / 64.0f);
}

// ---------------------------------------------------------------------------
// Weight prep: fold recurrence (W0' = W0 - W2), pad, split to bf16 hi/lo;
// zero the 5 x 32 x 128 replica BN-stats accumulators.
// ---------------------------------------------------------------------------
__global__ void k_prep(const float* __restrict__ c1w, const float* __restrict__ c2w,
                       const float* __restrict__ c3w, const float* __restrict__ e1t,
                       const float* __restrict__ e1p, const float* __restrict__ e2t,
                       const float* __restrict__ e2p, u16* __restrict__ W1h,
                       u16* __restrict__ W1l, u16* __restrict__ W2h,
                       u16* __restrict__ W2l, u16* __restrict__ W3h,
                       u16* __restrict__ W3l, u16* __restrict__ T1h,
                       u16* __restrict__ T1l, u16* __restrict__ P1h,
                       u16* __restrict__ P1l, u16* __restrict__ T2h,
                       u16* __restrict__ T2l, u16* __restrict__ P2h,
                       u16* __restrict__ P2l, float* __restrict__ stats) {
  int t0 = blockIdx.x * 256 + threadIdx.x;
  int stride = gridDim.x * 256;
  for (int i = t0; i < 5 * NREP * 128; i += stride) stats[i] = 0.f;
  for (int i = t0; i < 4096; i += stride) {  // cheb1: 64 x 64 (K padded)
    int r = i >> 6, c = i & 63;
    float v = 0.f;
    if (c < 16) v = c1w[r * 48 + c] - c1w[r * 48 + 32 + c];
    else if (c < 48) v = c1w[r * 48 + c];
    u16 h, l; split2(v, h, l); W1h[i] = h; W1l[i] = l;
  }
  for (int i = t0; i < 12288; i += stride) {  // cheb2: 64 x 192
    int r = i / 192, c = i - r * 192;
    float v = (c < 64) ? c2w[r * 192 + c] - c2w[r * 192 + 128 + c]
                       : c2w[r * 192 + c];
    u16 h, l; split2(v, h, l); W2h[i] = h; W2l[i] = l;
  }
  for (int i = t0; i < 12288; i += stride) {  // cheb3
    int r = i / 192, c = i - r * 192;
    float v = (c < 64) ? c3w[r * 192 + c] - c3w[r * 192 + 128 + c]
                       : c3w[r * 192 + c];
    u16 h, l; split2(v, h, l); W3h[i] = h; W3l[i] = l;
  }
  for (int i = t0; i < 4096; i += stride) {
    u16 h, l;
    split2(e1t[i], h, l); T1h[i] = h; T1l[i] = l;
    split2(e1p[i], h, l); P1h[i] = h; P1l[i] = l;
    split2(e2t[i], h, l); T2h[i] = h; T2l[i] = l;
    split2(e2p[i], h, l); P2h[i] = h; P2l[i] = l;
  }
}

// ---------------------------------------------------------------------------
extern "C" void kernel_launch(void* const* d_in, const int* in_sizes, int n_in,
                              void* d_out, int out_size, void* d_ws,
                              size_t ws_size, hipStream_t stream) {
  const float* feat = (const float*)d_in[0];
  const int* src = (const int*)d_in[1];
  const float* cheb1_w = (const float*)d_in[4];
  const float* cheb1_b = (const float*)d_in[5];
  const float* bn1_g = (const float*)d_in[6];
  const float* bn1_b = (const float*)d_in[7];
  const float* e1_tw = (const float*)d_in[8];
  const float* e1_tb = (const float*)d_in[9];
  const float* e1_pw = (const float*)d_in[10];
  const float* e1_pb = (const float*)d_in[11];
  const float* bne1_g = (const float*)d_in[12];
  const float* bne1_b = (const float*)d_in[13];
  const float* cheb2_w = (const float*)d_in[14];
  const float* cheb2_b = (const float*)d_in[15];
  const float* bn2_g = (const float*)d_in[16];
  const float* bn2_b = (const float*)d_in[17];
  const float* e2_tw = (const float*)d_in[18];
  const float* e2_tb = (const float*)d_in[19];
  const float* e2_pw = (const float*)d_in[20];
  const float* e2_pb = (const float*)d_in[21];
  const float* bne2_g = (const float*)d_in[22];
  const float* bne2_b = (const float*)d_in[23];
  const float* cheb3_w = (const float*)d_in[24];
  const float* cheb3_b = (const float*)d_in[25];
  const float* bn3_g = (const float*)d_in[26];
  const float* bn3_b = (const float*)d_in[27];

  float* bufA = (float*)d_ws;
  float* bufB = bufA + (size_t)NN * HH;
  float* stats = bufB + (size_t)NN * HH;  // 5 x NREP x 128 replica stats
  u16* wq = (u16*)(stats + 5 * NREP * 128);
  u16* W1h = wq;           u16* W1l = W1h + 4096;
  u16* W2h = W1l + 4096;   u16* W2l = W2h + 12288;
  u16* W3h = W2l + 12288;  u16* W3l = W3h + 12288;
  u16* T1h = W3l + 12288;  u16* T1l = T1h + 4096;
  u16* P1h = T1l + 4096;   u16* P1l = P1h + 4096;
  u16* T2h = P1l + 4096;   u16* T2l = T2h + 4096;
  u16* P2h = T2l + 4096;   u16* P2l = P2h + 4096;

  k_prep<<<16, 256, 0, stream>>>(cheb1_w, cheb2_w, cheb3_w, e1_tw, e1_pw,
                                 e2_tw, e2_pw, W1h, W1l, W2h, W2l, W3h, W3l,
                                 T1h, T1l, P1h, P1l, T2h, T2l, P2h, P2l,
                                 stats);

  k_cheb1<<<NG, 256, 0, stream>>>(feat, src, W1h, W1l, cheb1_b, bufA,
                                  stats + 0 * NREP * 128);
  k_econv<<<NG, 256, 0, stream>>>(bufA, stats + 0 * NREP * 128, bn1_g, bn1_b,
                                  src, T1h, T1l, P1h, P1l, e1_tb, e1_pb, bufB,
                                  stats + 1 * NREP * 128);
  k_cheb64<<<NG, 256, 0, stream>>>(bufB, stats + 1 * NREP * 128, bne1_g,
                                   bne1_b, src, W2h, W2l, cheb2_b, bufA,
                                   stats + 2 * NREP * 128);
  k_econv<<<NG, 256, 0, stream>>>(bufA, stats + 2 * NREP * 128, bn2_g, bn2_b,
                                  src, T2h, T2l, P2h, P2l, e2_tb, e2_pb, bufB,
                                  stats + 3 * NREP * 128);
  k_cheb64<<<NG, 256, 0, stream>>>(bufB, stats + 3 * NREP * 128, bne2_g,
                                   bne2_b, src, W3h, W3l, cheb3_b, bufA,
                                   stats + 4 * NREP * 128);
  k_pool<<<NG, 256, 0, stream>>>(bufA, stats + 4 * NREP * 128, bn3_g, bn3_b,
                                 (float*)d_out);
}